// Round 3
// baseline (1145.053 us; speedup 1.0000x reference)
//
#include <hip/hip_runtime.h>
#include <math.h>

#define BB 16
#define SS 64
#define NN 128
#define FF 16
#define HH 64
#define EE 1024
#define ET 1152   // EE + NN self-loops
#define LLAYERS 2
#define XPAD 65   // padded LDS row stride for xl/xr (bank = (s+h)%32)

__device__ __forceinline__ float readlane_f(float v, int k) {
  return __int_as_float(__builtin_amdgcn_readlane(__float_as_int(v), k));
}
// monotonic float<->uint mapping for atomicMax-based float max
__device__ __forceinline__ unsigned flipf(float f) {
  unsigned u = __float_as_uint(f);
  unsigned mask = (u & 0x80000000u) ? 0xFFFFFFFFu : 0x80000000u;
  return u ^ mask;
}
__device__ __forceinline__ float unflipf(unsigned u) {
  unsigned b = (u & 0x80000000u) ? (u ^ 0x80000000u) : ~u;
  return __uint_as_float(b);
}
__device__ __forceinline__ float sigmoidf_(float x) { return 1.f / (1.f + expf(-x)); }

// ---------------- CSR setup (graph is identical for every (b,s)) -------------
__global__ void setup_csr_kernel(const int* __restrict__ ei,
                                 int* __restrict__ off,
                                 int* __restrict__ csrc,
                                 int* __restrict__ ctgt) {
  __shared__ int deg[NN], cur[NN], offs[NN + 1];
  int tid = threadIdx.x;
  if (tid < NN) deg[tid] = 0;
  __syncthreads();
  for (int e = tid; e < ET; e += 256) {
    int tg = (e < EE) ? ei[EE + e] : (e - EE);
    atomicAdd(&deg[tg], 1);
  }
  __syncthreads();
  if (tid == 0) {
    int s = 0;
    for (int i = 0; i < NN; ++i) { offs[i] = s; s += deg[i]; }
    offs[NN] = s;
  }
  __syncthreads();
  if (tid < NN) cur[tid] = offs[tid];
  if (tid <= NN) off[tid] = offs[tid];
  __syncthreads();
  for (int e = tid; e < ET; e += 256) {
    int sv, tg;
    if (e < EE) { sv = ei[e]; tg = ei[EE + e]; }
    else        { sv = e - EE; tg = e - EE; }
    int pos = atomicAdd(&cur[tg], 1);
    csrc[pos] = sv;
    ctgt[pos] = tg;
  }
}

// ---------------- input projection: h = x @ W^T + b --------------------------
__global__ __launch_bounds__(256) void input_proj_kernel(
    const float* __restrict__ x, const float* __restrict__ W,
    const float* __restrict__ bvec, float* __restrict__ h) {
  int lane = threadIdx.x & 63;
  int wid = threadIdx.x >> 6;
  float wreg[FF];
#pragma unroll
  for (int i = 0; i < FF / 4; ++i)
    *(float4*)&wreg[4 * i] = ((const float4*)(W + lane * FF))[i];
  float bias = bvec[lane];
  int row0 = __builtin_amdgcn_readfirstlane((blockIdx.x * 4 + wid) * 32);
#pragma unroll 2
  for (int r = 0; r < 32; ++r) {
    int row = row0 + r;
    const float* xr = x + row * FF;
    float acc = bias;
#pragma unroll
    for (int f = 0; f < FF; ++f) acc += xr[f] * wreg[f];
    h[row * HH + lane] = acc;
  }
}

// ---------------- GAT kernel A: xl = h@Wl^T+bl, xr = h@Wr^T+br ---------------
__global__ __launch_bounds__(256) void xlxr_kernel(
    const float* __restrict__ hin,
    const float* __restrict__ Wl, const float* __restrict__ bl,
    const float* __restrict__ Wr, const float* __restrict__ br,
    float* __restrict__ xl, float* __restrict__ xr) {
  int lane = threadIdx.x & 63;
  int wid = (int)threadIdx.x >> 6;              // 0..3
  const float* W  = (wid & 1) ? Wr : Wl;
  const float* bv = (wid & 1) ? br : bl;
  float* outp     = (wid & 1) ? xr : xl;
  float w[HH];
#pragma unroll
  for (int i = 0; i < HH / 4; ++i)
    *(float4*)&w[4 * i] = ((const float4*)(W + lane * HH))[i];
  float bias = bv[lane];
  int row0 = __builtin_amdgcn_readfirstlane(blockIdx.x * 64 + (wid >> 1) * 32);
#pragma unroll 2
  for (int r = 0; r < 32; ++r) {
    const float* hrow = hin + (size_t)(row0 + r) * HH;
    float a0 = bias, a1 = 0.f, a2 = 0.f, a3 = 0.f;
#pragma unroll
    for (int f = 0; f < HH; f += 4) {
      a0 += hrow[f + 0] * w[f + 0];
      a1 += hrow[f + 1] * w[f + 1];
      a2 += hrow[f + 2] * w[f + 2];
      a3 += hrow[f + 3] * w[f + 3];
    }
    outp[(size_t)(row0 + r) * HH + lane] = (a0 + a1) + (a2 + a3);
  }
}

// ---------------- GAT kernel B: edge logits + softmax + aggregate ------------
__global__ __launch_bounds__(256) void gat_edge_kernel(
    const float* __restrict__ xl_g, const float* __restrict__ xr_g,
    float* __restrict__ hout,
    const int* __restrict__ csr_off, const int* __restrict__ csr_src,
    const int* __restrict__ csr_tgt,
    const float* __restrict__ att, const float* __restrict__ bo) {
  __shared__ float xl_sh[NN * XPAD];   // 33.3 KB
  __shared__ float xr_sh[NN * XPAD];   // 33.3 KB
  __shared__ float p_sh[ET];
  __shared__ int st_sh[ET];
  __shared__ unsigned m_sh[NN];
  int tid = threadIdx.x, lane = tid & 63, wid = tid >> 6;
  int base = blockIdx.x * (NN * HH);

  // stage xl/xr with padded stride
#pragma unroll 1
  for (int i = tid * 4; i < NN * HH; i += 256 * 4) {
    int row = i >> 6, h = i & 63;
    float4 vl = *(const float4*)(xl_g + base + i);
    float4 vr = *(const float4*)(xr_g + base + i);
    float* dl = xl_sh + row * XPAD + h;
    float* dr = xr_sh + row * XPAD + h;
    dl[0] = vl.x; dl[1] = vl.y; dl[2] = vl.z; dl[3] = vl.w;
    dr[0] = vr.x; dr[1] = vr.y; dr[2] = vr.z; dr[3] = vr.w;
  }
  for (int i = tid; i < ET; i += 256)
    st_sh[i] = csr_src[i] | (csr_tgt[i] << 16);
  if (tid < NN) m_sh[tid] = 0u;
  __syncthreads();

  // pass 1: thread-per-edge attention logit + segment max
#pragma unroll 1
  for (int e = tid; e < ET; e += 256) {
    int st = st_sh[e];
    int s = st & 0xffff, tg = st >> 16;
    const float* xlr = xl_sh + s * XPAD;
    const float* xrr = xr_sh + tg * XPAD;
    float a0 = 0.f, a1 = 0.f, a2 = 0.f, a3 = 0.f;
#pragma unroll
    for (int h = 0; h < HH; h += 4) {
      float v0 = xlr[h + 0] + xrr[h + 0]; v0 = (v0 > 0.f) ? v0 : 0.2f * v0;
      float v1 = xlr[h + 1] + xrr[h + 1]; v1 = (v1 > 0.f) ? v1 : 0.2f * v1;
      float v2 = xlr[h + 2] + xrr[h + 2]; v2 = (v2 > 0.f) ? v2 : 0.2f * v2;
      float v3 = xlr[h + 3] + xrr[h + 3]; v3 = (v3 > 0.f) ? v3 : 0.2f * v3;
      a0 += v0 * att[h + 0];
      a1 += v1 * att[h + 1];
      a2 += v2 * att[h + 2];
      a3 += v3 * att[h + 3];
    }
    float a = (a0 + a1) + (a2 + a3);
    p_sh[e] = a;
    atomicMax(&m_sh[tg], flipf(a));
  }
  __syncthreads();

  // pass 2: stabilized exp
  for (int e = tid; e < ET; e += 256) {
    int tg = st_sh[e] >> 16;
    p_sh[e] = expf(p_sh[e] - unflipf(m_sh[tg]));
  }
  __syncthreads();

  // gather: wave per target node, CSR-contiguous edge segment
  float bo_l = bo[lane];
#pragma unroll 1
  for (int n = wid; n < NN; n += 4) {
    int o0 = __builtin_amdgcn_readfirstlane(csr_off[n]);
    int o1 = __builtin_amdgcn_readfirstlane(csr_off[n + 1]);
    float acc = 0.f, z = 0.f;
    for (int i = o0; i < o1; ++i) {
      float p = p_sh[i];
      int s = st_sh[i] & 0xffff;
      acc += p * xl_sh[s * XPAD + lane];
      z += p;
    }
    float o = acc / z + bo_l;
    hout[base + n * HH + lane] = fmaxf(o, 0.f);
  }
}

// ---------------- fallback fused GAT (used if ws too small) ------------------
__device__ __forceinline__ void gemm_half(
    const float* __restrict__ hin, int base,
    const float* __restrict__ W, const float* __restrict__ bvec,
    float* __restrict__ out_sh, int half, int lane) {
  float wreg[HH];
#pragma unroll
  for (int i = 0; i < HH / 4; ++i)
    *(float4*)&wreg[4 * i] = ((const float4*)(W + lane * HH))[i];
  float bias = bvec[lane];
  int n0 = __builtin_amdgcn_readfirstlane(half * 64);
#pragma unroll 1
  for (int nd = 0; nd < 64; ++nd) {
    int node = n0 + nd;
    const float* hrow = hin + base + node * HH;
    float a0 = bias, a1 = 0.f, a2 = 0.f, a3 = 0.f;
#pragma unroll
    for (int f = 0; f < HH; f += 4) {
      a0 += hrow[f + 0] * wreg[f + 0];
      a1 += hrow[f + 1] * wreg[f + 1];
      a2 += hrow[f + 2] * wreg[f + 2];
      a3 += hrow[f + 3] * wreg[f + 3];
    }
    out_sh[node * HH + lane] = (a0 + a1) + (a2 + a3);
  }
}

__global__ __launch_bounds__(256) void gat_fused_kernel(
    const float* __restrict__ hin, float* __restrict__ hout,
    const int* __restrict__ csr_off, const int* __restrict__ csr_src,
    const int* __restrict__ csr_tgt,
    const float* __restrict__ Wl, const float* __restrict__ bl,
    const float* __restrict__ Wr, const float* __restrict__ br,
    const float* __restrict__ att, const float* __restrict__ bo) {
  __shared__ float xl_sh[NN * HH];
  __shared__ float xr_sh[NN * HH];
  __shared__ float p_sh[ET];
  __shared__ int st_sh[ET];
  __shared__ unsigned m_sh[NN];
  int tid = threadIdx.x, lane = tid & 63, wid = tid >> 6;
  int base = blockIdx.x * (NN * HH);

  for (int i = tid; i < ET; i += 256)
    st_sh[i] = csr_src[i] | (csr_tgt[i] << 16);
  if (tid < NN) m_sh[tid] = 0u;

  if (wid < 2) gemm_half(hin, base, Wl, bl, xl_sh, wid & 1, lane);
  else         gemm_half(hin, base, Wr, br, xr_sh, wid & 1, lane);

  float att_l = att[lane];
  float bo_l = bo[lane];
  __syncthreads();

#pragma unroll 1
  for (int e = wid; e < ET; e += 4) {
    int st = st_sh[e];
    int s = st & 0xffff, tg = st >> 16;
    float v = xl_sh[s * HH + lane] + xr_sh[tg * HH + lane];
    v = (v > 0.f) ? v : 0.2f * v;
    float prod = v * att_l;
#pragma unroll
    for (int mm = 32; mm; mm >>= 1) prod += __shfl_xor(prod, mm);
    if (lane == 0) {
      p_sh[e] = prod;
      atomicMax(&m_sh[tg], flipf(prod));
    }
  }
  __syncthreads();

  for (int e = tid; e < ET; e += 256) {
    int tg = st_sh[e] >> 16;
    p_sh[e] = expf(p_sh[e] - unflipf(m_sh[tg]));
  }
  __syncthreads();

#pragma unroll 1
  for (int n = wid; n < NN; n += 4) {
    int o0 = csr_off[n], o1 = csr_off[n + 1];
    float acc = 0.f, z = 0.f;
    for (int i = o0; i < o1; ++i) {
      float p = p_sh[i];
      int s = st_sh[i] & 0xffff;
      acc += p * xl_sh[s * HH + lane];
      z += p;
    }
    float o = acc / z + bo_l;
    hout[base + n * HH + lane] = fmaxf(o, 0.f);
  }
}

// ---------------- GRU part A (parallel): gi = x @ Wih^T + bih ----------------
// Block = 3 waves (one per gate), each block covers 32 rows of hbuf.
// Output layout: gi[seq][t][g*64+j], seq = b*N+n  -> coalesced 256B stores.
__global__ __launch_bounds__(192, 4) void gru_gi_kernel(
    const float* __restrict__ hbuf, const float* __restrict__ Wih,
    const float* __restrict__ bih, float* __restrict__ gi) {
  int lane = threadIdx.x & 63;
  int g = (int)threadIdx.x >> 6;     // gate 0=r 1=z 2=n
  int grow = g * 64 + lane;
  float w[HH];
#pragma unroll
  for (int i = 0; i < HH / 4; ++i)
    *(float4*)&w[4 * i] = ((const float4*)(Wih + grow * HH))[i];
  float bias = bih[grow];
  int r0 = __builtin_amdgcn_readfirstlane(blockIdx.x * 32);
#pragma unroll 2
  for (int rr = 0; rr < 32; ++rr) {
    int row = r0 + rr;                       // (b*SS+t)*NN + n
    const float* xr = hbuf + (size_t)row * HH;
    float a0 = bias, a1 = 0.f, a2 = 0.f, a3 = 0.f;
#pragma unroll
    for (int k = 0; k < HH; k += 4) {
      a0 += xr[k + 0] * w[k + 0];
      a1 += xr[k + 1] * w[k + 1];
      a2 += xr[k + 2] * w[k + 2];
      a3 += xr[k + 3] * w[k + 3];
    }
    int n = row & (NN - 1);
    int bt = row >> 7;                       // b*SS + t
    int b = bt >> 6, t = bt & (SS - 1);
    int seq = b * NN + n;
    gi[((size_t)seq * SS + t) * 192 + g * 64 + lane] = (a0 + a1) + (a2 + a3);
  }
}

// ---------------- GRU part B (recurrent) + fused heads -----------------------
// One wave per sequence; lane = j. All 3 Whh rows (192 floats) register-
// resident (__launch_bounds__(64,2) -> 256-VGPR cap). h broadcast via
// wave-uniform float4 LDS reads (DS pipe). Zero barriers (single wave).
__global__ __launch_bounds__(64, 2) void gru_rec_kernel(
    const float* __restrict__ gi,
    const float* __restrict__ Whh, const float* __restrict__ bhh,
    const float* __restrict__ oW1, const float* __restrict__ ob1,
    const float* __restrict__ oW2, const float* __restrict__ ob2,
    const float* __restrict__ dW1, const float* __restrict__ db1,
    const float* __restrict__ dW2, const float* __restrict__ db2,
    float* __restrict__ out) {
  int lane = threadIdx.x;            // j
  int seq = blockIdx.x;              // b*N + n
  float wr[HH], wz[HH], wn[HH];
#pragma unroll
  for (int i = 0; i < HH / 4; ++i) {
    *(float4*)&wr[4 * i] = ((const float4*)(Whh + (size_t)lane * HH))[i];
    *(float4*)&wz[4 * i] = ((const float4*)(Whh + (size_t)(64 + lane) * HH))[i];
    *(float4*)&wn[4 * i] = ((const float4*)(Whh + (size_t)(128 + lane) * HH))[i];
  }
  float br = bhh[lane], bz = bhh[64 + lane], bn = bhh[128 + lane];
  __shared__ float hsh[HH];
  hsh[lane] = 0.f;
  float hj = 0.f;
  const float* gseq = gi + (size_t)seq * SS * 192;
  __syncthreads();
#pragma unroll 1
  for (int t = 0; t < SS; ++t) {
    const float* gp = gseq + t * 192;
    float gir = gp[lane], giz = gp[lane + 64], gin = gp[lane + 128];
    float ar0 = br, ar1 = 0.f, ar2 = 0.f, ar3 = 0.f;
    float az0 = bz, az1 = 0.f, az2 = 0.f, az3 = 0.f;
    float an0 = bn, an1 = 0.f, an2 = 0.f, an3 = 0.f;
#pragma unroll
    for (int k = 0; k < HH; k += 4) {
      float4 hb = *(const float4*)(hsh + k);   // wave-uniform -> HW broadcast
      ar0 += hb.x * wr[k + 0]; az0 += hb.x * wz[k + 0]; an0 += hb.x * wn[k + 0];
      ar1 += hb.y * wr[k + 1]; az1 += hb.y * wz[k + 1]; an1 += hb.y * wn[k + 1];
      ar2 += hb.z * wr[k + 2]; az2 += hb.z * wz[k + 2]; an2 += hb.z * wn[k + 2];
      ar3 += hb.w * wr[k + 3]; az3 += hb.w * wz[k + 3]; an3 += hb.w * wn[k + 3];
    }
    float ghr = (ar0 + ar1) + (ar2 + ar3);
    float ghz = (az0 + az1) + (az2 + az3);
    float ghn = (an0 + an1) + (an2 + an3);
    float rg = sigmoidf_(gir + ghr);
    float zg = sigmoidf_(giz + ghz);
    float ng = tanhf(gin + rg * ghn);
    hj = (1.f - zg) * ng + zg * hj;
    hsh[lane] = hj;                  // single-wave lockstep: no barrier needed
  }
  // fused heads: lanes 0..31 = order head, lanes 32..63 = demand head
  int half = lane >> 5, jp = lane & 31;
  const float* W1 = half ? dW1 : oW1;
  const float* b1 = half ? db1 : ob1;
  const float* W2 = half ? dW2 : oW2;
  const float* b2 = half ? db2 : ob2;
  float wv[HH];
#pragma unroll
  for (int i = 0; i < HH / 4; ++i)
    *(float4*)&wv[4 * i] = ((const float4*)(W1 + jp * HH))[i];
  float acc = b1[jp];
#pragma unroll
  for (int k = 0; k < HH; k += 4) {
    float4 hb = *(const float4*)(hsh + k);
    acc += hb.x * wv[k + 0];
    acc += hb.y * wv[k + 1];
    acc += hb.z * wv[k + 2];
    acc += hb.w * wv[k + 3];
  }
  float val = fmaxf(acc, 0.f) * W2[jp];
  val += __shfl_down(val, 16, 32);
  val += __shfl_down(val, 8, 32);
  val += __shfl_down(val, 4, 32);
  val += __shfl_down(val, 2, 32);
  val += __shfl_down(val, 1, 32);
  if (jp == 0) out[half * (BB * NN) + seq] = val + b2[0];
}

// ---------------- fallback GRU (round-2 kernel, used if ws too small) --------
__device__ __forceinline__ void head_store(
    float hlast, const float* __restrict__ W1, const float* __restrict__ b1,
    const float* __restrict__ W2, const float* __restrict__ b2,
    float* __restrict__ outp, int lane) {
  int j = lane & 31;
  float wr[HH];
#pragma unroll
  for (int i = 0; i < HH / 4; ++i)
    *(float4*)&wr[4 * i] = ((const float4*)(W1 + j * HH))[i];
  float acc = b1[j];
#pragma unroll
  for (int k = 0; k < HH; ++k)
    acc += readlane_f(hlast, k) * wr[k];
  float val = fmaxf(acc, 0.f) * W2[j];
  val += __shfl_down(val, 16, 32);
  val += __shfl_down(val, 8, 32);
  val += __shfl_down(val, 4, 32);
  val += __shfl_down(val, 2, 32);
  val += __shfl_down(val, 1, 32);
  if (lane == 0) *outp = val + b2[0];
}

__global__ __launch_bounds__(192) void gru_head_kernel(
    const float* __restrict__ hbuf,
    const float* __restrict__ Wih, const float* __restrict__ Whh,
    const float* __restrict__ bih, const float* __restrict__ bhh,
    const float* __restrict__ oW1, const float* __restrict__ ob1,
    const float* __restrict__ oW2, const float* __restrict__ ob2,
    const float* __restrict__ dW1, const float* __restrict__ db1,
    const float* __restrict__ dW2, const float* __restrict__ db2,
    float* __restrict__ out) {
  int tid = threadIdx.x, lane = tid & 63, wid = tid >> 6;
  int seq = blockIdx.x;
  int b = seq >> 7, n = seq & 127;
  int grow = wid * 64 + lane;
  float wi[HH], wh[HH];
#pragma unroll
  for (int i = 0; i < HH / 4; ++i) {
    *(float4*)&wi[4 * i] = ((const float4*)(Wih + grow * HH))[i];
    *(float4*)&wh[4 * i] = ((const float4*)(Whh + grow * HH))[i];
  }
  float bi = bih[grow], bh = bhh[grow];
  __shared__ float r_sh[HH], z_sh[HH], hsh[HH];
  float hprev = 0.f;
#pragma unroll 1
  for (int t = 0; t < SS; ++t) {
    const float* xrow = hbuf + (size_t)((b * SS + t) * NN + n) * HH;
    float xv = xrow[lane];
    float ai0 = bi, ai1 = 0.f, ah0 = bh, ah1 = 0.f;
#pragma unroll
    for (int k = 0; k < HH; k += 2) {
      float xk0 = readlane_f(xv, k),     hk0 = readlane_f(hprev, k);
      float xk1 = readlane_f(xv, k + 1), hk1 = readlane_f(hprev, k + 1);
      ai0 += xk0 * wi[k];     ah0 += hk0 * wh[k];
      ai1 += xk1 * wi[k + 1]; ah1 += hk1 * wh[k + 1];
    }
    float ai = ai0 + ai1, ah = ah0 + ah1;
    if (wid == 0)      r_sh[lane] = sigmoidf_(ai + ah);
    else if (wid == 1) z_sh[lane] = sigmoidf_(ai + ah);
    __syncthreads();
    if (wid == 2) {
      float nn = tanhf(ai + r_sh[lane] * ah);
      float zz = z_sh[lane];
      hsh[lane] = (1.f - zz) * nn + zz * hprev;
    }
    __syncthreads();
    hprev = hsh[lane];
  }
  if (wid == 0)      head_store(hprev, oW1, ob1, oW2, ob2, out + seq, lane);
  else if (wid == 1) head_store(hprev, dW1, db1, dW2, db2, out + BB * NN + seq, lane);
}

// ---------------- launch -----------------------------------------------------
extern "C" void kernel_launch(void* const* d_in, const int* in_sizes, int n_in,
                              void* d_out, int out_size, void* d_ws, size_t ws_size,
                              hipStream_t stream) {
  const float* x       = (const float*)d_in[0];
  const int*   ei      = (const int*)d_in[1];
  const float* in_W    = (const float*)d_in[2];
  const float* in_b    = (const float*)d_in[3];
  const float* gat_Wl  = (const float*)d_in[4];
  const float* gat_bl  = (const float*)d_in[5];
  const float* gat_Wr  = (const float*)d_in[6];
  const float* gat_br  = (const float*)d_in[7];
  const float* gat_att = (const float*)d_in[8];
  const float* gat_bias= (const float*)d_in[9];
  const float* gru_Wih = (const float*)d_in[10];
  const float* gru_Whh = (const float*)d_in[11];
  const float* gru_bih = (const float*)d_in[12];
  const float* gru_bhh = (const float*)d_in[13];
  const float* oh_W1   = (const float*)d_in[14];
  const float* oh_b1   = (const float*)d_in[15];
  const float* oh_W2   = (const float*)d_in[16];
  const float* oh_b2   = (const float*)d_in[17];
  const float* dh_W1   = (const float*)d_in[18];
  const float* dh_b1   = (const float*)d_in[19];
  const float* dh_W2   = (const float*)d_in[20];
  const float* dh_b2   = (const float*)d_in[21];
  float* out = (float*)d_out;

  char* ws = (char*)d_ws;
  size_t hfloats = (size_t)BB * SS * NN * HH;           // 8.39M floats
  float* hbuf = (float*)ws;
  size_t off_csr = hfloats * sizeof(float);
  size_t off_buf = off_csr + (160 + 2 * ET) * sizeof(int);
  off_buf = (off_buf + 255) & ~(size_t)255;             // 256B align
  int* csr_off = (int*)(ws + off_csr);
  int* csr_src = csr_off + 160;
  int* csr_tgt = csr_src + ET;
  float* xlbuf = (float*)(ws + off_buf);
  float* xrbuf = xlbuf + hfloats;
  float* gibuf = (float*)(ws + off_buf);                // overlaps xl/xr (dead by GRU)
  size_t gi_bytes = (size_t)BB * NN * SS * 192 * sizeof(float);   // ~100.7 MB
  size_t need_gat = off_buf + 2 * hfloats * sizeof(float);
  size_t need_gru = off_buf + gi_bytes;
  bool big_gat = (ws_size >= need_gat);
  bool big_gru = (ws_size >= need_gru);

  setup_csr_kernel<<<1, 256, 0, stream>>>(ei, csr_off, csr_src, csr_tgt);
  input_proj_kernel<<<(BB * SS * NN) / (4 * 32), 256, 0, stream>>>(x, in_W, in_b, hbuf);
  for (int l = 0; l < LLAYERS; ++l) {
    if (big_gat) {
      xlxr_kernel<<<(BB * SS * NN) / 64, 256, 0, stream>>>(
          hbuf, gat_Wl + l * HH * HH, gat_bl + l * HH,
          gat_Wr + l * HH * HH, gat_br + l * HH, xlbuf, xrbuf);
      gat_edge_kernel<<<BB * SS, 256, 0, stream>>>(
          xlbuf, xrbuf, hbuf, csr_off, csr_src, csr_tgt,
          gat_att + l * HH, gat_bias + l * HH);
    } else {
      gat_fused_kernel<<<BB * SS, 256, 0, stream>>>(
          hbuf, hbuf, csr_off, csr_src, csr_tgt,
          gat_Wl + l * HH * HH, gat_bl + l * HH,
          gat_Wr + l * HH * HH, gat_br + l * HH,
          gat_att + l * HH, gat_bias + l * HH);
    }
  }
  if (big_gru) {
    gru_gi_kernel<<<(BB * SS * NN) / 32, 192, 0, stream>>>(
        hbuf, gru_Wih, gru_bih, gibuf);
    gru_rec_kernel<<<BB * NN, 64, 0, stream>>>(
        gibuf, gru_Whh, gru_bhh,
        oh_W1, oh_b1, oh_W2, oh_b2, dh_W1, dh_b1, dh_W2, dh_b2, out);
  } else {
    gru_head_kernel<<<BB * NN, 192, 0, stream>>>(
        hbuf, gru_Wih, gru_Whh, gru_bih, gru_bhh,
        oh_W1, oh_b1, oh_W2, oh_b2, dh_W1, dh_b1, dh_W2, dh_b2, out);
  }
}

// Round 4
// 686.572 us; speedup vs baseline: 1.6678x; 1.6678x over previous
//
#include <hip/hip_runtime.h>
#include <math.h>

#define BB 16
#define SS 64
#define NN 128
#define FF 16
#define HH 64
#define EE 1024
#define ET 1152   // EE + NN self-loops
#define LLAYERS 2
#define XPAD 65   // padded LDS row stride for xl/xr (bank = (s+h)%32)

__device__ __forceinline__ float readlane_f(float v, int k) {
  return __int_as_float(__builtin_amdgcn_readlane(__float_as_int(v), k));
}
// monotonic float<->uint mapping for atomicMax-based float max
__device__ __forceinline__ unsigned flipf(float f) {
  unsigned u = __float_as_uint(f);
  unsigned mask = (u & 0x80000000u) ? 0xFFFFFFFFu : 0x80000000u;
  return u ^ mask;
}
__device__ __forceinline__ float unflipf(unsigned u) {
  unsigned b = (u & 0x80000000u) ? (u ^ 0x80000000u) : ~u;
  return __uint_as_float(b);
}
__device__ __forceinline__ float sigmoidf_(float x) { return 1.f / (1.f + expf(-x)); }

// ---------------- CSR setup (graph is identical for every (b,s)) -------------
__global__ void setup_csr_kernel(const int* __restrict__ ei,
                                 int* __restrict__ off,
                                 int* __restrict__ csrc,
                                 int* __restrict__ ctgt) {
  __shared__ int deg[NN], cur[NN], offs[NN + 1];
  int tid = threadIdx.x;
  if (tid < NN) deg[tid] = 0;
  __syncthreads();
  for (int e = tid; e < ET; e += 256) {
    int tg = (e < EE) ? ei[EE + e] : (e - EE);
    atomicAdd(&deg[tg], 1);
  }
  __syncthreads();
  if (tid == 0) {
    int s = 0;
    for (int i = 0; i < NN; ++i) { offs[i] = s; s += deg[i]; }
    offs[NN] = s;
  }
  __syncthreads();
  if (tid < NN) cur[tid] = offs[tid];
  if (tid <= NN) off[tid] = offs[tid];
  __syncthreads();
  for (int e = tid; e < ET; e += 256) {
    int sv, tg;
    if (e < EE) { sv = ei[e]; tg = ei[EE + e]; }
    else        { sv = e - EE; tg = e - EE; }
    int pos = atomicAdd(&cur[tg], 1);
    csrc[pos] = sv;
    ctgt[pos] = tg;
  }
}

// ---------------- input projection: h = x @ W^T + b --------------------------
__global__ __launch_bounds__(256) void input_proj_kernel(
    const float* __restrict__ x, const float* __restrict__ W,
    const float* __restrict__ bvec, float* __restrict__ h) {
  int lane = threadIdx.x & 63;
  int wid = threadIdx.x >> 6;
  float wreg[FF];
#pragma unroll
  for (int i = 0; i < FF / 4; ++i)
    *(float4*)&wreg[4 * i] = ((const float4*)(W + lane * FF))[i];
  float bias = bvec[lane];
  int row0 = __builtin_amdgcn_readfirstlane((blockIdx.x * 4 + wid) * 32);
#pragma unroll 2
  for (int r = 0; r < 32; ++r) {
    int row = row0 + r;
    const float* xr = x + row * FF;
    float acc = bias;
#pragma unroll
    for (int f = 0; f < FF; ++f) acc += xr[f] * wreg[f];
    h[row * HH + lane] = acc;
  }
}

// ---------------- GAT kernel A: xl = h@Wl^T+bl, xr = h@Wr^T+br ---------------
__global__ __launch_bounds__(256) void xlxr_kernel(
    const float* __restrict__ hin,
    const float* __restrict__ Wl, const float* __restrict__ bl,
    const float* __restrict__ Wr, const float* __restrict__ br,
    float* __restrict__ xl, float* __restrict__ xr) {
  int lane = threadIdx.x & 63;
  int wid = (int)threadIdx.x >> 6;              // 0..3
  const float* W  = (wid & 1) ? Wr : Wl;
  const float* bv = (wid & 1) ? br : bl;
  float* outp     = (wid & 1) ? xr : xl;
  float w[HH];
#pragma unroll
  for (int i = 0; i < HH / 4; ++i)
    *(float4*)&w[4 * i] = ((const float4*)(W + lane * HH))[i];
  float bias = bv[lane];
  int row0 = __builtin_amdgcn_readfirstlane(blockIdx.x * 64 + (wid >> 1) * 32);
#pragma unroll 2
  for (int r = 0; r < 32; ++r) {
    const float* hrow = hin + (size_t)(row0 + r) * HH;
    float a0 = bias, a1 = 0.f, a2 = 0.f, a3 = 0.f;
#pragma unroll
    for (int f = 0; f < HH; f += 4) {
      a0 += hrow[f + 0] * w[f + 0];
      a1 += hrow[f + 1] * w[f + 1];
      a2 += hrow[f + 2] * w[f + 2];
      a3 += hrow[f + 3] * w[f + 3];
    }
    outp[(size_t)(row0 + r) * HH + lane] = (a0 + a1) + (a2 + a3);
  }
}

// ---------------- GAT kernel B: edge logits + softmax + aggregate ------------
__global__ __launch_bounds__(256) void gat_edge_kernel(
    const float* __restrict__ xl_g, const float* __restrict__ xr_g,
    float* __restrict__ hout,
    const int* __restrict__ csr_off, const int* __restrict__ csr_src,
    const int* __restrict__ csr_tgt,
    const float* __restrict__ att, const float* __restrict__ bo) {
  __shared__ float xl_sh[NN * XPAD];   // 33.3 KB
  __shared__ float xr_sh[NN * XPAD];   // 33.3 KB
  __shared__ float p_sh[ET];
  __shared__ int st_sh[ET];
  __shared__ unsigned m_sh[NN];
  int tid = threadIdx.x, lane = tid & 63, wid = tid >> 6;
  int base = blockIdx.x * (NN * HH);

  // stage xl/xr with padded stride
#pragma unroll 1
  for (int i = tid * 4; i < NN * HH; i += 256 * 4) {
    int row = i >> 6, h = i & 63;
    float4 vl = *(const float4*)(xl_g + base + i);
    float4 vr = *(const float4*)(xr_g + base + i);
    float* dl = xl_sh + row * XPAD + h;
    float* dr = xr_sh + row * XPAD + h;
    dl[0] = vl.x; dl[1] = vl.y; dl[2] = vl.z; dl[3] = vl.w;
    dr[0] = vr.x; dr[1] = vr.y; dr[2] = vr.z; dr[3] = vr.w;
  }
  for (int i = tid; i < ET; i += 256)
    st_sh[i] = csr_src[i] | (csr_tgt[i] << 16);
  if (tid < NN) m_sh[tid] = 0u;
  __syncthreads();

  // pass 1: thread-per-edge attention logit + segment max
#pragma unroll 1
  for (int e = tid; e < ET; e += 256) {
    int st = st_sh[e];
    int s = st & 0xffff, tg = st >> 16;
    const float* xlr = xl_sh + s * XPAD;
    const float* xrr = xr_sh + tg * XPAD;
    float a0 = 0.f, a1 = 0.f, a2 = 0.f, a3 = 0.f;
#pragma unroll
    for (int h = 0; h < HH; h += 4) {
      float v0 = xlr[h + 0] + xrr[h + 0]; v0 = (v0 > 0.f) ? v0 : 0.2f * v0;
      float v1 = xlr[h + 1] + xrr[h + 1]; v1 = (v1 > 0.f) ? v1 : 0.2f * v1;
      float v2 = xlr[h + 2] + xrr[h + 2]; v2 = (v2 > 0.f) ? v2 : 0.2f * v2;
      float v3 = xlr[h + 3] + xrr[h + 3]; v3 = (v3 > 0.f) ? v3 : 0.2f * v3;
      a0 += v0 * att[h + 0];
      a1 += v1 * att[h + 1];
      a2 += v2 * att[h + 2];
      a3 += v3 * att[h + 3];
    }
    float a = (a0 + a1) + (a2 + a3);
    p_sh[e] = a;
    atomicMax(&m_sh[tg], flipf(a));
  }
  __syncthreads();

  // pass 2: stabilized exp
  for (int e = tid; e < ET; e += 256) {
    int tg = st_sh[e] >> 16;
    p_sh[e] = expf(p_sh[e] - unflipf(m_sh[tg]));
  }
  __syncthreads();

  // gather: wave per target node, CSR-contiguous edge segment
  float bo_l = bo[lane];
#pragma unroll 1
  for (int n = wid; n < NN; n += 4) {
    int o0 = __builtin_amdgcn_readfirstlane(csr_off[n]);
    int o1 = __builtin_amdgcn_readfirstlane(csr_off[n + 1]);
    float acc = 0.f, z = 0.f;
    for (int i = o0; i < o1; ++i) {
      float p = p_sh[i];
      int s = st_sh[i] & 0xffff;
      acc += p * xl_sh[s * XPAD + lane];
      z += p;
    }
    float o = acc / z + bo_l;
    hout[base + n * HH + lane] = fmaxf(o, 0.f);
  }
}

// ---------------- fallback fused GAT (used if ws too small) ------------------
__device__ __forceinline__ void gemm_half(
    const float* __restrict__ hin, int base,
    const float* __restrict__ W, const float* __restrict__ bvec,
    float* __restrict__ out_sh, int half, int lane) {
  float wreg[HH];
#pragma unroll
  for (int i = 0; i < HH / 4; ++i)
    *(float4*)&wreg[4 * i] = ((const float4*)(W + lane * HH))[i];
  float bias = bvec[lane];
  int n0 = __builtin_amdgcn_readfirstlane(half * 64);
#pragma unroll 1
  for (int nd = 0; nd < 64; ++nd) {
    int node = n0 + nd;
    const float* hrow = hin + base + node * HH;
    float a0 = bias, a1 = 0.f, a2 = 0.f, a3 = 0.f;
#pragma unroll
    for (int f = 0; f < HH; f += 4) {
      a0 += hrow[f + 0] * wreg[f + 0];
      a1 += hrow[f + 1] * wreg[f + 1];
      a2 += hrow[f + 2] * wreg[f + 2];
      a3 += hrow[f + 3] * wreg[f + 3];
    }
    out_sh[node * HH + lane] = (a0 + a1) + (a2 + a3);
  }
}

__global__ __launch_bounds__(256) void gat_fused_kernel(
    const float* __restrict__ hin, float* __restrict__ hout,
    const int* __restrict__ csr_off, const int* __restrict__ csr_src,
    const int* __restrict__ csr_tgt,
    const float* __restrict__ Wl, const float* __restrict__ bl,
    const float* __restrict__ Wr, const float* __restrict__ br,
    const float* __restrict__ att, const float* __restrict__ bo) {
  __shared__ float xl_sh[NN * HH];
  __shared__ float xr_sh[NN * HH];
  __shared__ float p_sh[ET];
  __shared__ int st_sh[ET];
  __shared__ unsigned m_sh[NN];
  int tid = threadIdx.x, lane = tid & 63, wid = tid >> 6;
  int base = blockIdx.x * (NN * HH);

  for (int i = tid; i < ET; i += 256)
    st_sh[i] = csr_src[i] | (csr_tgt[i] << 16);
  if (tid < NN) m_sh[tid] = 0u;

  if (wid < 2) gemm_half(hin, base, Wl, bl, xl_sh, wid & 1, lane);
  else         gemm_half(hin, base, Wr, br, xr_sh, wid & 1, lane);

  float att_l = att[lane];
  float bo_l = bo[lane];
  __syncthreads();

#pragma unroll 1
  for (int e = wid; e < ET; e += 4) {
    int st = st_sh[e];
    int s = st & 0xffff, tg = st >> 16;
    float v = xl_sh[s * HH + lane] + xr_sh[tg * HH + lane];
    v = (v > 0.f) ? v : 0.2f * v;
    float prod = v * att_l;
#pragma unroll
    for (int mm = 32; mm; mm >>= 1) prod += __shfl_xor(prod, mm);
    if (lane == 0) {
      p_sh[e] = prod;
      atomicMax(&m_sh[tg], flipf(prod));
    }
  }
  __syncthreads();

  for (int e = tid; e < ET; e += 256) {
    int tg = st_sh[e] >> 16;
    p_sh[e] = expf(p_sh[e] - unflipf(m_sh[tg]));
  }
  __syncthreads();

#pragma unroll 1
  for (int n = wid; n < NN; n += 4) {
    int o0 = csr_off[n], o1 = csr_off[n + 1];
    float acc = 0.f, z = 0.f;
    for (int i = o0; i < o1; ++i) {
      float p = p_sh[i];
      int s = st_sh[i] & 0xffff;
      acc += p * xl_sh[s * HH + lane];
      z += p;
    }
    float o = acc / z + bo_l;
    hout[base + n * HH + lane] = fmaxf(o, 0.f);
  }
}

// ---------------- GRU: producer-consumer, 2 waves per sequence ---------------
// Wave 0 (producer): holds 3 Wih rows/lane (192 VGPRs), computes
// gi(t+1) = x_{t+1}@Wih^T + bih one step ahead, into a 2-slot LDS ring.
// Wave 1 (consumer): holds 3 Whh rows/lane, recurrent gates via readlane
// broadcast of its own h_j register. One barrier per step. No global
// intermediates: reads hbuf directly (L2/L3-friendly, ~17 MB fetch).
// __launch_bounds__(128,2) -> 256-VGPR cap so weight arrays stay resident.
__global__ __launch_bounds__(128, 2) void gru_pc_kernel(
    const float* __restrict__ hbuf,
    const float* __restrict__ Wih, const float* __restrict__ Whh,
    const float* __restrict__ bih, const float* __restrict__ bhh,
    const float* __restrict__ oW1, const float* __restrict__ ob1,
    const float* __restrict__ oW2, const float* __restrict__ ob2,
    const float* __restrict__ dW1, const float* __restrict__ db1,
    const float* __restrict__ dW2, const float* __restrict__ db2,
    float* __restrict__ out) {
  int lane = threadIdx.x & 63;
  int w = (int)threadIdx.x >> 6;     // 0 = producer (ih), 1 = consumer (hh)
  int seq = blockIdx.x;              // b*N + n
  int b = seq >> 7, n = seq & (NN - 1);

  __shared__ float ring[2][3][HH];   // [slot][gate][j]
  __shared__ float hsh[HH];

  const float* Wsel = w ? Whh : Wih;
  const float* Bsel = w ? bhh : bih;
  float wt[3][HH];                   // 192 floats, register-resident
#pragma unroll
  for (int g = 0; g < 3; ++g) {
    const float4* src = (const float4*)(Wsel + (size_t)(g * 64 + lane) * HH);
#pragma unroll
    for (int i = 0; i < HH / 4; ++i)
      *(float4*)&wt[g][4 * i] = src[i];
  }
  float b_r = Bsel[lane], b_z = Bsel[64 + lane], b_n = Bsel[128 + lane];

  const float* xbase = hbuf + ((size_t)(b * SS) * NN + n) * HH;  // +t*NN*HH
  float hj = 0.f;

  // prologue: producer fills slot 0 with gi(t=0)
  if (w == 0) {
    float xv = xbase[lane];          // coalesced 256B
    float ar0 = b_r, ar1 = 0.f, az0 = b_z, az1 = 0.f, an0 = b_n, an1 = 0.f;
#pragma unroll
    for (int k = 0; k < HH; k += 2) {
      float x0 = readlane_f(xv, k), x1 = readlane_f(xv, k + 1);
      ar0 += x0 * wt[0][k];     az0 += x0 * wt[1][k];     an0 += x0 * wt[2][k];
      ar1 += x1 * wt[0][k + 1]; az1 += x1 * wt[1][k + 1]; an1 += x1 * wt[2][k + 1];
    }
    ring[0][0][lane] = ar0 + ar1;
    ring[0][1][lane] = az0 + az1;
    ring[0][2][lane] = an0 + an1;
  }
  __syncthreads();

#pragma unroll 1
  for (int t = 0; t < SS; ++t) {
    if (w == 0) {
      if (t + 1 < SS) {
        const float* xr = xbase + (size_t)(t + 1) * NN * HH;
        float xv = xr[lane];
        float ar0 = b_r, ar1 = 0.f, az0 = b_z, az1 = 0.f, an0 = b_n, an1 = 0.f;
#pragma unroll
        for (int k = 0; k < HH; k += 2) {
          float x0 = readlane_f(xv, k), x1 = readlane_f(xv, k + 1);
          ar0 += x0 * wt[0][k];     az0 += x0 * wt[1][k];     an0 += x0 * wt[2][k];
          ar1 += x1 * wt[0][k + 1]; az1 += x1 * wt[1][k + 1]; an1 += x1 * wt[2][k + 1];
        }
        int slot = (t + 1) & 1;
        ring[slot][0][lane] = ar0 + ar1;
        ring[slot][1][lane] = az0 + az1;
        ring[slot][2][lane] = an0 + an1;
      }
    } else {
      int slot = t & 1;
      float gir = ring[slot][0][lane];
      float giz = ring[slot][1][lane];
      float gin = ring[slot][2][lane];
      float ar0 = b_r, ar1 = 0.f, az0 = b_z, az1 = 0.f, an0 = b_n, an1 = 0.f;
#pragma unroll
      for (int k = 0; k < HH; k += 2) {
        float h0 = readlane_f(hj, k), h1 = readlane_f(hj, k + 1);
        ar0 += h0 * wt[0][k];     az0 += h0 * wt[1][k];     an0 += h0 * wt[2][k];
        ar1 += h1 * wt[0][k + 1]; az1 += h1 * wt[1][k + 1]; an1 += h1 * wt[2][k + 1];
      }
      float ghr = ar0 + ar1, ghz = az0 + az1, ghn = an0 + an1;
      float rg = sigmoidf_(gir + ghr);
      float zg = sigmoidf_(giz + ghz);
      float ng = tanhf(gin + rg * ghn);
      hj = (1.f - zg) * ng + zg * hj;
    }
    __syncthreads();
  }

  if (w == 1) hsh[lane] = hj;
  __syncthreads();

  // fused heads on wave 1: lanes 0..31 = order head, 32..63 = demand head
  if (w == 1) {
    int half = lane >> 5, jp = lane & 31;
    const float* W1 = half ? dW1 : oW1;
    const float* b1 = half ? db1 : ob1;
    const float* W2 = half ? dW2 : oW2;
    const float* b2 = half ? db2 : ob2;
    float wv[HH];
#pragma unroll
    for (int i = 0; i < HH / 4; ++i)
      *(float4*)&wv[4 * i] = ((const float4*)(W1 + jp * HH))[i];
    float acc = b1[jp];
#pragma unroll
    for (int k = 0; k < HH; k += 4) {
      float4 hb = *(const float4*)(hsh + k);   // wave-uniform broadcast
      acc += hb.x * wv[k + 0];
      acc += hb.y * wv[k + 1];
      acc += hb.z * wv[k + 2];
      acc += hb.w * wv[k + 3];
    }
    float val = fmaxf(acc, 0.f) * W2[jp];
    val += __shfl_down(val, 16, 32);
    val += __shfl_down(val, 8, 32);
    val += __shfl_down(val, 4, 32);
    val += __shfl_down(val, 2, 32);
    val += __shfl_down(val, 1, 32);
    if (jp == 0) out[half * (BB * NN) + seq] = val + b2[0];
  }
}

// ---------------- launch -----------------------------------------------------
extern "C" void kernel_launch(void* const* d_in, const int* in_sizes, int n_in,
                              void* d_out, int out_size, void* d_ws, size_t ws_size,
                              hipStream_t stream) {
  const float* x       = (const float*)d_in[0];
  const int*   ei      = (const int*)d_in[1];
  const float* in_W    = (const float*)d_in[2];
  const float* in_b    = (const float*)d_in[3];
  const float* gat_Wl  = (const float*)d_in[4];
  const float* gat_bl  = (const float*)d_in[5];
  const float* gat_Wr  = (const float*)d_in[6];
  const float* gat_br  = (const float*)d_in[7];
  const float* gat_att = (const float*)d_in[8];
  const float* gat_bias= (const float*)d_in[9];
  const float* gru_Wih = (const float*)d_in[10];
  const float* gru_Whh = (const float*)d_in[11];
  const float* gru_bih = (const float*)d_in[12];
  const float* gru_bhh = (const float*)d_in[13];
  const float* oh_W1   = (const float*)d_in[14];
  const float* oh_b1   = (const float*)d_in[15];
  const float* oh_W2   = (const float*)d_in[16];
  const float* oh_b2   = (const float*)d_in[17];
  const float* dh_W1   = (const float*)d_in[18];
  const float* dh_b1   = (const float*)d_in[19];
  const float* dh_W2   = (const float*)d_in[20];
  const float* dh_b2   = (const float*)d_in[21];
  float* out = (float*)d_out;

  char* ws = (char*)d_ws;
  size_t hfloats = (size_t)BB * SS * NN * HH;           // 8.39M floats
  float* hbuf = (float*)ws;
  size_t off_csr = hfloats * sizeof(float);
  size_t off_buf = off_csr + (160 + 2 * ET) * sizeof(int);
  off_buf = (off_buf + 255) & ~(size_t)255;             // 256B align
  int* csr_off = (int*)(ws + off_csr);
  int* csr_src = csr_off + 160;
  int* csr_tgt = csr_src + ET;
  float* xlbuf = (float*)(ws + off_buf);
  float* xrbuf = xlbuf + hfloats;
  size_t need_gat = off_buf + 2 * hfloats * sizeof(float);
  bool big_gat = (ws_size >= need_gat);

  setup_csr_kernel<<<1, 256, 0, stream>>>(ei, csr_off, csr_src, csr_tgt);
  input_proj_kernel<<<(BB * SS * NN) / (4 * 32), 256, 0, stream>>>(x, in_W, in_b, hbuf);
  for (int l = 0; l < LLAYERS; ++l) {
    if (big_gat) {
      xlxr_kernel<<<(BB * SS * NN) / 64, 256, 0, stream>>>(
          hbuf, gat_Wl + l * HH * HH, gat_bl + l * HH,
          gat_Wr + l * HH * HH, gat_br + l * HH, xlbuf, xrbuf);
      gat_edge_kernel<<<BB * SS, 256, 0, stream>>>(
          xlbuf, xrbuf, hbuf, csr_off, csr_src, csr_tgt,
          gat_att + l * HH, gat_bias + l * HH);
    } else {
      gat_fused_kernel<<<BB * SS, 256, 0, stream>>>(
          hbuf, hbuf, csr_off, csr_src, csr_tgt,
          gat_Wl + l * HH * HH, gat_bl + l * HH,
          gat_Wr + l * HH * HH, gat_br + l * HH,
          gat_att + l * HH, gat_bias + l * HH);
    }
  }
  gru_pc_kernel<<<BB * NN, 128, 0, stream>>>(
      hbuf, gru_Wih, gru_Whh, gru_bih, gru_bhh,
      oh_W1, oh_b1, oh_W2, oh_b2, dh_W1, dh_b1, dh_W2, dh_b2, out);
}